// Round 4
// baseline (2559.172 us; speedup 1.0000x reference)
//
#include <hip/hip_runtime.h>
#include <math.h>

typedef unsigned long long ulong_t;

#define Bsz 64
#define Tlen 1024
#define Idim 256
#define Hdim 512
#define Odim 256

#define PB  2              // batches per sync-group
#define NSL 8              // column slices = WGs per group (64 cols each)
#define NG  (Bsz / PB)     // 32 groups -> 256 WGs total

// ---------------------------------------------------------------------------
// Kernel A: xproj[b][t][h] = dot(x[b, t0+t, :], Wi[h, :]) + bi[h] + bh[h]
// GEMM M=(Bsz*CT) x N=512, K=256. Tile 128x128, 256 threads.
// ---------------------------------------------------------------------------
__global__ __launch_bounds__(256) void xproj_kernel(
        const float* __restrict__ x, const float* __restrict__ Wi,
        const float* __restrict__ bi, const float* __restrict__ bh,
        float* __restrict__ xp, int t0, int CT) {
    __shared__ float As[16][132];
    __shared__ float Bs[16][132];
    const int tid = threadIdx.x;
    const int bm = blockIdx.x, bn = blockIdx.y;
    const int tx = tid & 15, ty = tid >> 4;

    const int f0 = tid, f1 = tid + 256;
    const int ar0 = f0 >> 2, ak0 = (f0 & 3) * 4;
    const int ar1 = f1 >> 2, ak1 = (f1 & 3) * 4;
    const int m0g = bm * 128 + ar0;
    const int m1g = bm * 128 + ar1;
    const int b0 = m0g / CT, tt0 = m0g - b0 * CT;
    const int b1 = m1g / CT, tt1 = m1g - b1 * CT;
    const float* xrow0 = x + ((size_t)b0 * Tlen + t0 + tt0) * Idim;
    const float* xrow1 = x + ((size_t)b1 * Tlen + t0 + tt1) * Idim;
    const float* wrow0 = Wi + (size_t)(bn * 128 + ar0) * Idim;
    const float* wrow1 = Wi + (size_t)(bn * 128 + ar1) * Idim;

    float acc[8][8];
#pragma unroll
    for (int i = 0; i < 8; ++i)
#pragma unroll
        for (int j = 0; j < 8; ++j) acc[i][j] = 0.0f;

    for (int kk = 0; kk < Idim; kk += 16) {
        float4 av0 = *(const float4*)(xrow0 + kk + ak0);
        float4 av1 = *(const float4*)(xrow1 + kk + ak1);
        float4 bv0 = *(const float4*)(wrow0 + kk + ak0);
        float4 bv1 = *(const float4*)(wrow1 + kk + ak1);
        __syncthreads();
        As[ak0 + 0][ar0] = av0.x; As[ak0 + 1][ar0] = av0.y;
        As[ak0 + 2][ar0] = av0.z; As[ak0 + 3][ar0] = av0.w;
        As[ak1 + 0][ar1] = av1.x; As[ak1 + 1][ar1] = av1.y;
        As[ak1 + 2][ar1] = av1.z; As[ak1 + 3][ar1] = av1.w;
        Bs[ak0 + 0][ar0] = bv0.x; Bs[ak0 + 1][ar0] = bv0.y;
        Bs[ak0 + 2][ar0] = bv0.z; Bs[ak0 + 3][ar0] = bv0.w;
        Bs[ak1 + 0][ar1] = bv1.x; Bs[ak1 + 1][ar1] = bv1.y;
        Bs[ak1 + 2][ar1] = bv1.z; Bs[ak1 + 3][ar1] = bv1.w;
        __syncthreads();
#pragma unroll
        for (int k = 0; k < 16; ++k) {
            float4 a0 = *(const float4*)&As[k][tx * 4];
            float4 a1 = *(const float4*)&As[k][64 + tx * 4];
            float4 bq0 = *(const float4*)&Bs[k][ty * 4];
            float4 bq1 = *(const float4*)&Bs[k][64 + ty * 4];
            float a[8] = {a0.x, a0.y, a0.z, a0.w, a1.x, a1.y, a1.z, a1.w};
            float bb[8] = {bq0.x, bq0.y, bq0.z, bq0.w, bq1.x, bq1.y, bq1.z, bq1.w};
#pragma unroll
            for (int i = 0; i < 8; ++i)
#pragma unroll
                for (int j = 0; j < 8; ++j) acc[i][j] += a[i] * bb[j];
        }
    }

    const int n0 = bn * 128;
    float biasv[8];
#pragma unroll
    for (int j = 0; j < 8; ++j) {
        int c = (j < 4) ? (ty * 4 + j) : (64 + ty * 4 + (j - 4));
        biasv[j] = bi[n0 + c] + bh[n0 + c];
    }
#pragma unroll
    for (int i = 0; i < 8; ++i) {
        int r = (i < 4) ? (tx * 4 + i) : (64 + tx * 4 + (i - 4));
        size_t mrow = (size_t)(bm * 128 + r);
        float4 o0 = {acc[i][0] + biasv[0], acc[i][1] + biasv[1],
                     acc[i][2] + biasv[2], acc[i][3] + biasv[3]};
        float4 o1 = {acc[i][4] + biasv[4], acc[i][5] + biasv[5],
                     acc[i][6] + biasv[6], acc[i][7] + biasv[7]};
        *(float4*)(xp + mrow * Hdim + n0 + ty * 4) = o0;
        *(float4*)(xp + mrow * Hdim + n0 + 64 + ty * 4) = o1;
    }
}

// ---------------------------------------------------------------------------
// Kernel B: register-resident-Wh scan with SELF-VALIDATING TAGGED exchange.
// hglob is ulong[2][Bsz][Hdim]: hi 32b = step tag (t+1), lo 32b = float h.
// Per step: FMA partials (LDS-broadcast h) -> LDS reduce -> tanh ->
// one 8B tagged store per output (no drain barrier, no flags) -> peers
// poll tagged words directly (detect == deliver, one L3 round trip).
// Double-buffered by step parity; tag monotonicity makes reuse safe:
// a producer reaching step s+2 has consumed every peer's s+1 output.
// 0xAA ws poison can't false-positive a tag. Swizzle keeps a group's 8 WGs
// on one XCD for locality (perf only; correctness is agent-scope at L3).
// ---------------------------------------------------------------------------
__global__ __launch_bounds__(512) void scan_reg(
        const float* __restrict__ xp, const float* __restrict__ Wh,
        ulong_t* __restrict__ hglob, int t0, int CT) {
    const int wg = blockIdx.x;                        // 0..255
    const int g = (wg & 7) + ((wg >> 6) << 3);        // 0..31
    const int n = (wg >> 3) & 7;                      // 0..7
    const int colbase = n * 64;
    const int bbase = g * PB;
    const int tid = threadIdx.x;
    const int ct = tid & 15;                          // col-group 0..15
    const int kg = tid >> 4;                          // k-group 0..31

    // --- Wh fragment into registers (once): w[cc][i] ---
    float4 w[4][4];
#pragma unroll
    for (int cc = 0; cc < 4; ++cc) {
        const float4* src =
            (const float4*)(Wh + (size_t)(colbase + ct * 4 + cc) * Hdim + kg * 16);
#pragma unroll
        for (int i = 0; i < 4; ++i) w[cc][i] = src[i];
    }

    __shared__ float  hs[PB][Hdim];                   // 4 KB
    __shared__ float4 red4[PB][32][17];               // ~17.4 KB

    // --- poll-pair assignment: thread owns 2 adjacent h values ---
    const int pb_ = tid >> 8;                         // batch 0..1
    const int pc  = (tid & 255) * 2;                  // col (even)
    const bool foreign = ((pc >> 6) != n);

    // --- init h_{t0} into LDS (prev chunk's kernel completed -> plain reads) ---
    {
        float v0 = 0.f, v1 = 0.f;
        if (t0 != 0) {
            const ulong_t* a =
                hglob + (((size_t)(t0 & 1)) * Bsz + bbase + pb_) * Hdim + pc;
            v0 = __uint_as_float((unsigned)a[0]);
            v1 = __uint_as_float((unsigned)a[1]);
        }
        hs[pb_][pc] = v0;
        hs[pb_][pc + 1] = v1;
    }
    __syncthreads();

    const int fb = tid >> 6;                          // finalize batch (tid<128)
    const int fc = tid & 63;                          // finalize col-in-slice

    // prefetch xp for t=0
    float xv = 0.f;
    if (tid < 128)
        xv = xp[((size_t)(bbase + fb) * CT) * Hdim + colbase + fc];

    for (int t = 0; t < CT; ++t) {
        const int st = t0 + t;
        const int nb = (st + 1) & 1;                  // buffer for h_{st+1}

        // --- partial GEMV: register Wh x LDS-broadcast h ---
        float4 p0 = {0.f, 0.f, 0.f, 0.f};
        float4 p1 = {0.f, 0.f, 0.f, 0.f};
#pragma unroll
        for (int i = 0; i < 4; ++i) {
            float4 h0 = *(const float4*)&hs[0][kg * 16 + i * 4];
            float4 h1 = *(const float4*)&hs[1][kg * 16 + i * 4];
            p0.x += w[0][i].x * h0.x + w[0][i].y * h0.y + w[0][i].z * h0.z + w[0][i].w * h0.w;
            p0.y += w[1][i].x * h0.x + w[1][i].y * h0.y + w[1][i].z * h0.z + w[1][i].w * h0.w;
            p0.z += w[2][i].x * h0.x + w[2][i].y * h0.y + w[2][i].z * h0.z + w[2][i].w * h0.w;
            p0.w += w[3][i].x * h0.x + w[3][i].y * h0.y + w[3][i].z * h0.z + w[3][i].w * h0.w;
            p1.x += w[0][i].x * h1.x + w[0][i].y * h1.y + w[0][i].z * h1.z + w[0][i].w * h1.w;
            p1.y += w[1][i].x * h1.x + w[1][i].y * h1.y + w[1][i].z * h1.z + w[1][i].w * h1.w;
            p1.z += w[2][i].x * h1.x + w[2][i].y * h1.y + w[2][i].z * h1.z + w[2][i].w * h1.w;
            p1.w += w[3][i].x * h1.x + w[3][i].y * h1.y + w[3][i].z * h1.z + w[3][i].w * h1.w;
        }
        red4[0][kg][ct] = p0;
        red4[1][kg][ct] = p1;
        __syncthreads();                              // (A) partials visible

        // prefetch next xp early (overlaps reduce + store + poll)
        float xv_next = 0.f;
        if (tid < 128 && t + 1 < CT)
            xv_next = xp[((size_t)(bbase + fb) * CT + (t + 1)) * Hdim + colbase + fc];

        // --- finalize: reduce 32 k-groups, tanh, ONE tagged 8B store ---
        if (tid < 128) {
            float s = 0.f;
#pragma unroll
            for (int k = 0; k < 32; ++k)
                s += ((const float*)&red4[fb][k][0])[fc];
            float h1v = tanhf(s + xv);
            ulong_t pk = (((ulong_t)(unsigned)(st + 1)) << 32) |
                         (ulong_t)__float_as_uint(h1v);
            __hip_atomic_store(
                &hglob[((size_t)nb * Bsz + bbase + fb) * Hdim + colbase + fc],
                pk, __ATOMIC_RELAXED, __HIP_MEMORY_SCOPE_AGENT);
            hs[fb][colbase + fc] = h1v;               // own slice via LDS
        }
        xv = xv_next;

        if (t + 1 < CT) {
            // --- poll foreign tagged words: detect == deliver ---
            if (foreign) {
                ulong_t* a =
                    hglob + ((size_t)nb * Bsz + bbase + pb_) * Hdim + pc;
                const unsigned tagexp = (unsigned)(st + 1);
                ulong_t x0 = 0, x1 = 0;
                bool d0 = false, d1 = false;
                do {
                    if (!d0) {
                        x0 = __hip_atomic_load(a, __ATOMIC_RELAXED,
                                               __HIP_MEMORY_SCOPE_AGENT);
                        d0 = ((unsigned)(x0 >> 32) == tagexp);
                    }
                    if (!d1) {
                        x1 = __hip_atomic_load(a + 1, __ATOMIC_RELAXED,
                                               __HIP_MEMORY_SCOPE_AGENT);
                        d1 = ((unsigned)(x1 >> 32) == tagexp);
                    }
                } while (!(d0 && d1));
                hs[pb_][pc]     = __uint_as_float((unsigned)x0);
                hs[pb_][pc + 1] = __uint_as_float((unsigned)x1);
            }
            __syncthreads();                          // (D) h_{st+1} ready
        }
    }
}

// ---------------------------------------------------------------------------
// Kernel C: out[b][o] = dot(h_final[b,:], Wo[o,:]) + bo[o]
// h_final: tagged buffer parity (Tlen&1)==0 -> hglob base; lo 32b = value.
// ---------------------------------------------------------------------------
__global__ __launch_bounds__(256) void out_kernel(
        const ulong_t* __restrict__ hbuf, const float* __restrict__ Wo,
        const float* __restrict__ bo, float* __restrict__ out) {
    __shared__ float hsh[Hdim];
    const int b = blockIdx.x, o = threadIdx.x;
    hsh[o]       = __uint_as_float((unsigned)hbuf[(size_t)b * Hdim + o]);
    hsh[o + 256] = __uint_as_float((unsigned)hbuf[(size_t)b * Hdim + o + 256]);
    __syncthreads();
    const float4* wrow = (const float4*)(Wo + (size_t)o * Hdim);
    const float4* h4 = (const float4*)hsh;
    float4 a4 = {0.0f, 0.0f, 0.0f, 0.0f};
#pragma unroll 4
    for (int i = 0; i < Hdim / 4; ++i) {
        float4 ww = wrow[i];
        float4 hv = h4[i];
        a4.x += ww.x * hv.x;
        a4.y += ww.y * hv.y;
        a4.z += ww.z * hv.z;
        a4.w += ww.w * hv.w;
    }
    out[b * Odim + o] = bo[o] + ((a4.x + a4.y) + (a4.z + a4.w));
}

// ---------------------------------------------------------------------------
extern "C" void kernel_launch(void* const* d_in, const int* in_sizes, int n_in,
                              void* d_out, int out_size, void* d_ws, size_t ws_size,
                              hipStream_t stream) {
    const float* x  = (const float*)d_in[0];
    const float* Wi = (const float*)d_in[1];
    const float* bi = (const float*)d_in[2];
    const float* Wh = (const float*)d_in[3];
    const float* bh = (const float*)d_in[4];
    const float* Wo = (const float*)d_in[5];
    const float* bo = (const float*)d_in[6];
    float* out = (float*)d_out;

    const size_t hbytes = 2ull * Bsz * Hdim * sizeof(ulong_t);  // tagged dbuf
    int CT = Tlen;
    while (CT > 2 && (size_t)Bsz * CT * Hdim * sizeof(float) + hbytes > ws_size)
        CT >>= 1;

    float*   xp    = (float*)d_ws;
    ulong_t* hglob = (ulong_t*)((char*)d_ws + (size_t)Bsz * CT * Hdim * sizeof(float));

    for (int t0 = 0; t0 < Tlen; t0 += CT) {
        xproj_kernel<<<dim3((Bsz * CT) / 128, Hdim / 128), 256, 0, stream>>>(
            x, Wi, bi, bh, xp, t0, CT);
        scan_reg<<<dim3(NG * NSL), 512, 0, stream>>>(xp, Wh, hglob, t0, CT);
    }
    // final h tag = Tlen (even parity) -> buffer 0 = hglob base
    out_kernel<<<dim3(Bsz), 256, 0, stream>>>(hglob, Wo, bo, out);
}